// Round 1
// 916.101 us; speedup vs baseline: 1.0115x; 1.0115x over previous
//
#include <hip/hip_runtime.h>
#include <math.h>

#define NB 32
#define NC 64
#define HW 65536                     // 256*256 spatial elements per plane
#define CMID 4
#define CHUNK_B 8                    // batches per chunk: 8*64 planes * 256KiB = 128 MiB < 256 MiB L3
#define CHUNK_PLANES (CHUNK_B * NC)  // 512 planes per chunk
#define NCHUNK (NB / CHUNK_B)        // 4 chunks
#define QSIZE (HW / 4)               // 16384 floats per quarter-plane (64 KiB)

typedef float f4 __attribute__((ext_vector_type(4)));

// ---------------------------------------------------------------------------
// Kernel A: per-quarter-plane partial sums for one 8-batch chunk.
// grid = 2048 blocks (4 blocks/plane * 512 planes), 256 threads.
// Each block reads a contiguous 64 KiB quarter-plane (16 float4/thread).
// Reads allocate normally -> chunk lands in Infinity Cache for kernel B.
// partial[plane*4 + q] is written exactly once per iteration (no zeroing,
// no stale-workspace dependency).
// ---------------------------------------------------------------------------
__global__ __launch_bounds__(256) void se_pool_chunk(const float* __restrict__ in,
                                                     float* __restrict__ partial,
                                                     int base_plane) {
    const int plane = base_plane + (int)(blockIdx.x >> 2);
    const int q     = blockIdx.x & 3;
    const f4* p = (const f4*)(in + (size_t)plane * HW + (size_t)q * QSIZE);

    float sum = 0.f;
    #pragma unroll
    for (int i = 0; i < 16; ++i) {
        f4 v = p[i * 256 + threadIdx.x];
        sum += (v.x + v.y) + (v.z + v.w);
    }

    // wave64 reduce
    #pragma unroll
    for (int off = 32; off > 0; off >>= 1)
        sum += __shfl_down(sum, off, 64);

    __shared__ float ws[4];
    const int lane = threadIdx.x & 63;
    const int wid  = threadIdx.x >> 6;
    if (lane == 0) ws[wid] = sum;
    __syncthreads();
    if (threadIdx.x == 0)
        partial[plane * 4 + q] = (ws[0] + ws[1]) + (ws[2] + ws[3]);
}

// ---------------------------------------------------------------------------
// Kernel B: fused MLP + rescale for one chunk.
// grid = 2048 blocks (4 blocks/plane), 256 threads, 64 KiB/block.
// Each block redundantly computes the 64->4->64 channel MLP for its batch
// from the per-quarter partials (~800 L2-cached scalar loads — negligible),
// then rescales its quarter-plane. Input re-read hits L3 (chunk cached by
// kernel A); output uses nontemporal stores so it doesn't evict chunk data.
// ---------------------------------------------------------------------------
__global__ __launch_bounds__(256) void se_scale_chunk(const float* __restrict__ in,
                                                      const float* __restrict__ partial,
                                                      const float* __restrict__ w_down,
                                                      const float* __restrict__ b_down,
                                                      const float* __restrict__ w_up,
                                                      const float* __restrict__ b_up,
                                                      float* __restrict__ out,
                                                      int base_plane) {
    const int plane = base_plane + (int)(blockIdx.x >> 2);
    const int q     = blockIdx.x & 3;
    const int b     = plane >> 6;   // batch
    const int c     = plane & 63;   // channel of this block's plane
    const int t     = threadIdx.x;

    __shared__ float pb[NC];
    __shared__ float hid[CMID];
    __shared__ float s_scale;

    // pooled[b, t] = mean over plane (sum of its 4 quarter partials)
    if (t < NC) {
        f4 pq = ((const f4*)partial)[b * NC + t];
        pb[t] = (pq.x + pq.y + pq.z + pq.w) * (1.0f / (float)HW);
    }
    __syncthreads();

    // hidden[b, m] = relu(sum_c pooled[b,c] * w_down[m,c] + b_down[m])
    if (t < CMID) {
        float s = b_down[t];
        #pragma unroll
        for (int cc = 0; cc < NC; ++cc) s += pb[cc] * w_down[t * NC + cc];
        hid[t] = fmaxf(s, 0.f);
    }
    __syncthreads();

    // scale[b, c] = sigmoid(sum_m hidden[b,m] * w_up[c,m] + b_up[c])
    if (t == 0) {
        float s = b_up[c];
        #pragma unroll
        for (int m = 0; m < CMID; ++m) s += hid[m] * w_up[c * CMID + m];
        s_scale = 1.0f / (1.0f + __expf(-s));
    }
    __syncthreads();

    const float s = s_scale;
    const f4* ip = (const f4*)(in  + (size_t)plane * HW + (size_t)q * QSIZE);
    f4*       op = (f4*)      (out + (size_t)plane * HW + (size_t)q * QSIZE);
    #pragma unroll
    for (int i = 0; i < 16; ++i) {
        f4 v = ip[i * 256 + t];
        v *= s;
        __builtin_nontemporal_store(v, op + i * 256 + t);
    }
}

extern "C" void kernel_launch(void* const* d_in, const int* in_sizes, int n_in,
                              void* d_out, int out_size, void* d_ws, size_t ws_size,
                              hipStream_t stream) {
    const float* trans_b = (const float*)d_in[0];
    const float* w_down  = (const float*)d_in[1];
    const float* b_down  = (const float*)d_in[2];
    const float* w_up    = (const float*)d_in[3];
    const float* b_up    = (const float*)d_in[4];
    float* out = (float*)d_out;

    float* partial = (float*)d_ws;   // 2048 planes * 4 quarters = 8192 floats (32 KiB)

    // Chunked pipeline: pool chunk k, then immediately rescale chunk k while
    // its 128 MiB is still resident in the 256 MiB Infinity Cache.
    for (int k = 0; k < NCHUNK; ++k) {
        const int base = k * CHUNK_PLANES;
        se_pool_chunk<<<CHUNK_PLANES * 4, 256, 0, stream>>>(trans_b, partial, base);
        se_scale_chunk<<<CHUNK_PLANES * 4, 256, 0, stream>>>(trans_b, partial,
                                                             w_down, b_down, w_up, b_up,
                                                             out, base);
    }
}